// Round 2
// baseline (7629.855 us; speedup 1.0000x reference)
//
#include <hip/hip_runtime.h>

typedef unsigned short u16;
typedef __attribute__((ext_vector_type(8))) short short8;
typedef __attribute__((ext_vector_type(4))) float f32x4;

#define GLP(p) ((const __attribute__((address_space(1))) void*)(p))
#define LDSP(p) ((__attribute__((address_space(3))) void*)(p))

__device__ inline u16 f2bf(float f) {
  unsigned u = __float_as_uint(f);
  return (u16)((u + 0x7fffu + ((u >> 16) & 1u)) >> 16);
}
__device__ inline float bf2f(u16 h) {
  return __uint_as_float(((unsigned)h) << 16);
}
__device__ inline float tanh_fast(float x) {
  float e = __expf(2.0f * x);
  return 1.0f - 2.0f / (e + 1.0f);
}

// ---------------- prep: fp32 -> bf16 conversions, zero h buffers & barrier ----
__device__ inline void convseg(const float* __restrict__ s, u16* __restrict__ d,
                               long n4, long t, long S) {
  for (long i = t; i < n4; i += S) {
    float4 v = ((const float4*)s)[i];
    ushort4 o;
    o.x = f2bf(v.x); o.y = f2bf(v.y); o.z = f2bf(v.z); o.w = f2bf(v.w);
    ((ushort4*)d)[i] = o;
  }
}

__global__ __launch_bounds__(256) void prep_kernel(
    const float* __restrict__ x, const float* __restrict__ wih0,
    const float* __restrict__ whh0, const float* __restrict__ wih1,
    const float* __restrict__ whh1,
    u16* __restrict__ xb, u16* __restrict__ wih0b, u16* __restrict__ whh0b,
    u16* __restrict__ wih1b, u16* __restrict__ whh1b,
    u16* __restrict__ hbufs, int* __restrict__ bar) {
  long t = blockIdx.x * 256L + threadIdx.x;
  long S = (long)gridDim.x * 256L;
  convseg(x,    xb,    16777216 / 4, t, S);
  convseg(wih0, wih0b,   524288 / 4, t, S);
  convseg(whh0, whh0b,  1048576 / 4, t, S);
  convseg(wih1, wih1b,  1048576 / 4, t, S);
  convseg(whh1, whh1b,  1048576 / 4, t, S);
  // zero h1(2x) + h2(2x): 4*65536 u16 = 524288 B = 65536 ushort4
  ushort4 z4 = make_ushort4(0, 0, 0, 0);
  for (long i = t; i < 65536; i += S) ((ushort4*)hbufs)[i] = z4;
  for (long i = t; i < 512; i += S) bar[i] = 0;
}

// ---------------- GEMM: xp0[m][n] = sum_k x[m][k]*Wih0[n][k] + bih0[n]+bhh0[n]
// M=32768, N=1024, K=512; bf16 in, bf16 out (fp32 accum)
__global__ __launch_bounds__(256, 2) void gemm_xproj(
    const u16* __restrict__ A,   // 32768 x 512
    const u16* __restrict__ Bw,  // 1024 x 512
    const float* __restrict__ bi, const float* __restrict__ bh,
    u16* __restrict__ C) {       // 32768 x 1024
  __shared__ u16 As[128 * 64];
  __shared__ u16 Bs[128 * 64];
  const int tid = threadIdx.x;
  const int lane = tid & 63;
  const int w = tid >> 6;
  const int ln = lane & 15, kg = lane >> 4;
  const int m0 = blockIdx.x * 128;
  const int n0 = blockIdx.y * 128;
  const int mi = (w & 1) * 64, ni = (w >> 1) * 64;

  f32x4 acc[4][4] = {};
  float bias[4];
#pragma unroll
  for (int nj = 0; nj < 4; ++nj) bias[nj] = bi[n0 + ni + nj * 16 + ln] + bh[n0 + ni + nj * 16 + ln];

  const int lrow = lane >> 3;
  const int lcol = (lane & 7) * 8;

  for (int kt = 0; kt < 512; kt += 64) {
#pragma unroll
    for (int i = 0; i < 4; ++i) {
      int row = i * 32 + w * 8;
      const u16* ga = A + (long)(m0 + row + lrow) * 512 + kt + lcol;
      __builtin_amdgcn_global_load_lds(GLP(ga), LDSP(As + row * 64), 16, 0, 0);
      const u16* gb = Bw + (long)(n0 + row + lrow) * 512 + kt + lcol;
      __builtin_amdgcn_global_load_lds(GLP(gb), LDSP(Bs + row * 64), 16, 0, 0);
    }
    __syncthreads();
#pragma unroll
    for (int kc = 0; kc < 64; kc += 32) {
      short8 af[4], bf[4];
#pragma unroll
      for (int i = 0; i < 4; ++i) {
        af[i] = *(const short8*)(As + (mi + i * 16 + ln) * 64 + kc + kg * 8);
        bf[i] = *(const short8*)(Bs + (ni + i * 16 + ln) * 64 + kc + kg * 8);
      }
#pragma unroll
      for (int a = 0; a < 4; ++a)
#pragma unroll
        for (int b = 0; b < 4; ++b)
          acc[a][b] = __builtin_amdgcn_mfma_f32_16x16x32_bf16(af[a], bf[b], acc[a][b], 0, 0, 0);
    }
    __syncthreads();
  }
#pragma unroll
  for (int a = 0; a < 4; ++a)
#pragma unroll
    for (int b = 0; b < 4; ++b)
#pragma unroll
      for (int r = 0; r < 4; ++r) {
        int m = m0 + mi + a * 16 + kg * 4 + r;
        int n = n0 + ni + b * 16 + ln;
        C[(long)m * 1024 + n] = f2bf(acc[a][b][r] + bias[b]);
      }
}

// ---------------- custom grid barrier (256 blocks, all co-resident) ----------
// relaxed agent-scope atomics + __threadfence() (device-scope fence) for
// cross-XCD visibility; __hip_atomic_fence is not available in this ROCm.
__device__ inline void grid_barrier(int* gen, int* flags, int target) {
  if (blockIdx.x == 0) {
    if (threadIdx.x == 0) {
      __threadfence();
      __hip_atomic_store(&flags[0], target, __ATOMIC_RELAXED, __HIP_MEMORY_SCOPE_AGENT);
    }
    // 256 threads spin on the 256 per-block flags
    while (__hip_atomic_load(&flags[threadIdx.x], __ATOMIC_RELAXED, __HIP_MEMORY_SCOPE_AGENT) < target) {}
    __syncthreads();
    if (threadIdx.x == 0) {
      __hip_atomic_store(gen, target, __ATOMIC_RELAXED, __HIP_MEMORY_SCOPE_AGENT);
    }
    __threadfence();
    __syncthreads();
  } else {
    if (threadIdx.x == 0) {
      __threadfence();
      __hip_atomic_store(&flags[blockIdx.x], target, __ATOMIC_RELAXED, __HIP_MEMORY_SCOPE_AGENT);
      while (__hip_atomic_load(gen, __ATOMIC_RELAXED, __HIP_MEMORY_SCOPE_AGENT) < target) {}
      __threadfence();
    }
    __syncthreads();
  }
}

// ---------------- persistent pipelined 2-layer recurrence --------------------
// 256 blocks x 256 threads. block = (batch_tile q in 0..3) x (unit_tile c in 0..63)
// iteration it: layer0 computes h1[it] (it<512); layer1 computes h2[it-1] (it>=1)
__global__ __launch_bounds__(256, 2) void rnn_persist(
    const u16* __restrict__ whh0, const u16* __restrict__ wih1,
    const u16* __restrict__ whh1, const u16* __restrict__ xp0,
    const float* __restrict__ bih1, const float* __restrict__ bhh1,
    u16* __restrict__ h1buf, u16* __restrict__ h2buf, int* __restrict__ bar) {
  const int tid = threadIdx.x;
  const int lane = tid & 63;
  const int w = tid >> 6;
  const int ln = lane & 15, kg = lane >> 4;
  const int m0 = (blockIdx.x >> 6) * 16;
  const int j0 = (blockIdx.x & 63) * 16;
  const int kb = w * 256;  // this wave's K-chunk base (K split 4 ways)

  // persistent weight fragments (B-operand layout: n=lane&15 -> row j0+ln)
  short8 WA[8], W1[8], W2[8];
#pragma unroll
  for (int i = 0; i < 8; ++i) {
    int off = (j0 + ln) * 1024 + kb + i * 32 + kg * 8;
    WA[i] = *(const short8*)(whh0 + off);
    W1[i] = *(const short8*)(wih1 + off);
    W2[i] = *(const short8*)(whh1 + off);
  }
  const float bias1 = bih1[j0 + ln] + bhh1[j0 + ln];

  __shared__ float red[2][4][256];
  int* gen = bar;
  int* flags = bar + 64;
  const int hoff = (m0 + ln) * 1024 + kb + kg * 8;  // A-operand: m=lane&15 -> batch

  for (int it = 0; it <= 512; ++it) {
    const u16* h1p = h1buf + ((it + 1) & 1) * 65536;  // h1[it-1]
    const u16* h2p = h2buf + (it & 1) * 65536;        // h2[it-2]
    short8 H1[8], H2[8];
#pragma unroll
    for (int i = 0; i < 8; ++i) {
      H1[i] = *(const short8*)(h1p + hoff + i * 32);
      H2[i] = *(const short8*)(h2p + hoff + i * 32);
    }
    f32x4 accA = {}, accB = {};
#pragma unroll
    for (int i = 0; i < 8; ++i) accA = __builtin_amdgcn_mfma_f32_16x16x32_bf16(H1[i], WA[i], accA, 0, 0, 0);
#pragma unroll
    for (int i = 0; i < 8; ++i) accB = __builtin_amdgcn_mfma_f32_16x16x32_bf16(H1[i], W1[i], accB, 0, 0, 0);
#pragma unroll
    for (int i = 0; i < 8; ++i) accB = __builtin_amdgcn_mfma_f32_16x16x32_bf16(H2[i], W2[i], accB, 0, 0, 0);
    *(f32x4*)&red[0][w][lane * 4] = accA;
    *(f32x4*)&red[1][w][lane * 4] = accB;
    __syncthreads();

    if (w == 0) {
      if (it < 512) {  // epilogue layer 0 -> h1[it]
        f32x4 s = *(const f32x4*)&red[0][0][lane * 4];
        s += *(const f32x4*)&red[0][1][lane * 4];
        s += *(const f32x4*)&red[0][2][lane * 4];
        s += *(const f32x4*)&red[0][3][lane * 4];
        u16* h1w = h1buf + (it & 1) * 65536;
#pragma unroll
        for (int r = 0; r < 4; ++r) {
          int mb = m0 + kg * 4 + r;  // D layout: row=(lane>>4)*4+r, col=lane&15
          float z = s[r] + bf2f(xp0[((long)mb * 512 + it) * 1024 + j0 + ln]);
          h1w[mb * 1024 + j0 + ln] = f2bf(tanh_fast(z));
        }
      }
    } else if (w == 1) {
      if (it >= 1) {  // epilogue layer 1 -> h2[it-1]
        f32x4 s = *(const f32x4*)&red[1][0][lane * 4];
        s += *(const f32x4*)&red[1][1][lane * 4];
        s += *(const f32x4*)&red[1][2][lane * 4];
        s += *(const f32x4*)&red[1][3][lane * 4];
        u16* h2w = h2buf + ((it + 1) & 1) * 65536;
#pragma unroll
        for (int r = 0; r < 4; ++r) {
          int mb = m0 + kg * 4 + r;
          float z = s[r] + bias1;
          h2w[mb * 1024 + j0 + ln] = f2bf(tanh_fast(z));
        }
      }
    }
    __syncthreads();
    if (it < 512) grid_barrier(gen, flags, it + 1);
  }
}

// ---------------- FC head: out[b] = sigmoid(h2[511][b,:] . fc_w + fc_b) ------
__global__ __launch_bounds__(256) void fc_kernel(const u16* __restrict__ h2,
                                                 const float* __restrict__ fcw,
                                                 const float* __restrict__ fcb,
                                                 float* __restrict__ out) {
  const int lane = threadIdx.x & 63;
  const int w = threadIdx.x >> 6;
  float wreg[16];
#pragma unroll
  for (int i = 0; i < 16; ++i) wreg[i] = fcw[lane * 16 + i];
  for (int b = w; b < 64; b += 4) {
    const u16* hp = h2 + b * 1024 + lane * 16;
    float s = 0.f;
#pragma unroll
    for (int i = 0; i < 16; ++i) s += bf2f(hp[i]) * wreg[i];
#pragma unroll
    for (int off = 32; off > 0; off >>= 1) s += __shfl_down(s, off, 64);
    if (lane == 0) out[b] = 1.0f / (1.0f + __expf(-(s + fcb[0])));
  }
}

extern "C" void kernel_launch(void* const* d_in, const int* in_sizes, int n_in,
                              void* d_out, int out_size, void* d_ws, size_t ws_size,
                              hipStream_t stream) {
  const float* x    = (const float*)d_in[0];
  const float* wih0 = (const float*)d_in[1];
  const float* whh0 = (const float*)d_in[2];
  const float* bih0 = (const float*)d_in[3];
  const float* bhh0 = (const float*)d_in[4];
  const float* wih1 = (const float*)d_in[5];
  const float* whh1 = (const float*)d_in[6];
  const float* bih1 = (const float*)d_in[7];
  const float* bhh1 = (const float*)d_in[8];
  const float* fcw  = (const float*)d_in[9];
  const float* fcb  = (const float*)d_in[10];

  char* ws = (char*)d_ws;
  u16* xb    = (u16*)(ws);                  // 33,554,432 B
  u16* wih0b = (u16*)(ws + 33554432);       //  1,048,576 B
  u16* whh0b = (u16*)(ws + 34603008);       //  2,097,152 B
  u16* wih1b = (u16*)(ws + 36700160);       //  2,097,152 B
  u16* whh1b = (u16*)(ws + 38797312);       //  2,097,152 B
  u16* xp0   = (u16*)(ws + 40894464);       // 67,108,864 B
  u16* h1buf = (u16*)(ws + 108003328);      //    262,144 B (2 parities)
  u16* h2buf = (u16*)(ws + 108265472);      //    262,144 B (2 parities)
  int* bar   = (int*)(ws + 108527616);      //      2,048 B

  prep_kernel<<<1024, 256, 0, stream>>>(x, wih0, whh0, wih1, whh1, xb, wih0b,
                                        whh0b, wih1b, whh1b, h1buf, bar);
  dim3 gg(256, 8);
  gemm_xproj<<<gg, 256, 0, stream>>>(xb, wih0b, bih0, bhh0, xp0);
  rnn_persist<<<256, 256, 0, stream>>>(whh0b, wih1b, whh1b, xp0, bih1, bhh1,
                                       h1buf, h2buf, bar);
  fc_kernel<<<1, 256, 0, stream>>>(h2buf + 65536, fcw, fcb, (float*)d_out);
}

// Round 4
// 3563.503 us; speedup vs baseline: 2.1411x; 2.1411x over previous
//
#include <hip/hip_runtime.h>

typedef unsigned short u16;
typedef __attribute__((ext_vector_type(8))) short short8;
typedef __attribute__((ext_vector_type(4))) float f32x4;

#define GLP(p) ((const __attribute__((address_space(1))) void*)(p))
#define LDSP(p) ((__attribute__((address_space(3))) void*)(p))

__device__ inline u16 f2bf(float f) {
  unsigned u = __float_as_uint(f);
  return (u16)((u + 0x7fffu + ((u >> 16) & 1u)) >> 16);
}
__device__ inline float bf2f(u16 h) {
  return __uint_as_float(((unsigned)h) << 16);
}
__device__ inline float tanh_fast(float x) {
  float e = __expf(2.0f * x);
  return 1.0f - 2.0f / (e + 1.0f);
}

// ---- LLC-direct (coherence point) access helpers: sc0 sc1 bypass L1/L2 ------
__device__ inline void store_short_sc(u16* p, unsigned v) {
  asm volatile("global_store_short %0, %1, off sc0 sc1" :: "v"(p), "v"(v) : "memory");
}
__device__ inline void store_int_sc(int* p, int v) {
  asm volatile("global_store_dword %0, %1, off sc0 sc1" :: "v"(p), "v"(v) : "memory");
}
__device__ inline int load_int_sc(const int* p) {
  int v;
  asm volatile("global_load_dword %0, %1, off sc0 sc1\n\t"
               "s_waitcnt vmcnt(0)"
               : "=&v"(v) : "v"(p) : "memory");
  return v;
}
// 16 pipelined LLC loads (8 for H1 tile, 8 for H2 tile) + one drain.
// NOTE: "=&v" early-clobber is REQUIRED — global_load writes its dest
// asynchronously, so outputs must not alias the pointer inputs.
__device__ inline void load_h_tiles(const u16* p1, const u16* p2,
                                    short8& a0, short8& a1, short8& a2, short8& a3,
                                    short8& a4, short8& a5, short8& a6, short8& a7,
                                    short8& b0, short8& b1, short8& b2, short8& b3,
                                    short8& b4, short8& b5, short8& b6, short8& b7) {
  asm volatile(
      "global_load_dwordx4 %0, %16, off sc0 sc1\n\t"
      "global_load_dwordx4 %1, %16, off offset:64 sc0 sc1\n\t"
      "global_load_dwordx4 %2, %16, off offset:128 sc0 sc1\n\t"
      "global_load_dwordx4 %3, %16, off offset:192 sc0 sc1\n\t"
      "global_load_dwordx4 %4, %16, off offset:256 sc0 sc1\n\t"
      "global_load_dwordx4 %5, %16, off offset:320 sc0 sc1\n\t"
      "global_load_dwordx4 %6, %16, off offset:384 sc0 sc1\n\t"
      "global_load_dwordx4 %7, %16, off offset:448 sc0 sc1\n\t"
      "global_load_dwordx4 %8, %17, off sc0 sc1\n\t"
      "global_load_dwordx4 %9, %17, off offset:64 sc0 sc1\n\t"
      "global_load_dwordx4 %10, %17, off offset:128 sc0 sc1\n\t"
      "global_load_dwordx4 %11, %17, off offset:192 sc0 sc1\n\t"
      "global_load_dwordx4 %12, %17, off offset:256 sc0 sc1\n\t"
      "global_load_dwordx4 %13, %17, off offset:320 sc0 sc1\n\t"
      "global_load_dwordx4 %14, %17, off offset:384 sc0 sc1\n\t"
      "global_load_dwordx4 %15, %17, off offset:448 sc0 sc1\n\t"
      "s_waitcnt vmcnt(0)"
      : "=&v"(a0), "=&v"(a1), "=&v"(a2), "=&v"(a3),
        "=&v"(a4), "=&v"(a5), "=&v"(a6), "=&v"(a7),
        "=&v"(b0), "=&v"(b1), "=&v"(b2), "=&v"(b3),
        "=&v"(b4), "=&v"(b5), "=&v"(b6), "=&v"(b7)
      : "v"(p1), "v"(p2)
      : "memory");
}

// ---------------- prep: fp32 -> bf16 conversions, zero h buffers & barrier ----
__device__ inline void convseg(const float* __restrict__ s, u16* __restrict__ d,
                               long n4, long t, long S) {
  for (long i = t; i < n4; i += S) {
    float4 v = ((const float4*)s)[i];
    ushort4 o;
    o.x = f2bf(v.x); o.y = f2bf(v.y); o.z = f2bf(v.z); o.w = f2bf(v.w);
    ((ushort4*)d)[i] = o;
  }
}

__global__ __launch_bounds__(256) void prep_kernel(
    const float* __restrict__ x, const float* __restrict__ wih0,
    const float* __restrict__ whh0, const float* __restrict__ wih1,
    const float* __restrict__ whh1,
    u16* __restrict__ xb, u16* __restrict__ wih0b, u16* __restrict__ whh0b,
    u16* __restrict__ wih1b, u16* __restrict__ whh1b,
    u16* __restrict__ hbufs, int* __restrict__ bar) {
  long t = blockIdx.x * 256L + threadIdx.x;
  long S = (long)gridDim.x * 256L;
  convseg(x,    xb,    16777216 / 4, t, S);
  convseg(wih0, wih0b,   524288 / 4, t, S);
  convseg(whh0, whh0b,  1048576 / 4, t, S);
  convseg(wih1, wih1b,  1048576 / 4, t, S);
  convseg(whh1, whh1b,  1048576 / 4, t, S);
  // zero h1(2x) + h2(2x): 4*65536 u16 = 524288 B = 65536 ushort4
  ushort4 z4 = make_ushort4(0, 0, 0, 0);
  for (long i = t; i < 65536; i += S) ((ushort4*)hbufs)[i] = z4;
  for (long i = t; i < 512; i += S) bar[i] = 0;
}

// ---------------- GEMM: xp0[m][n] = sum_k x[m][k]*Wih0[n][k] + bih0[n]+bhh0[n]
// M=32768, N=1024, K=512; bf16 in, bf16 out (fp32 accum)
__global__ __launch_bounds__(256, 2) void gemm_xproj(
    const u16* __restrict__ A,   // 32768 x 512
    const u16* __restrict__ Bw,  // 1024 x 512
    const float* __restrict__ bi, const float* __restrict__ bh,
    u16* __restrict__ C) {       // 32768 x 1024
  __shared__ u16 As[128 * 64];
  __shared__ u16 Bs[128 * 64];
  const int tid = threadIdx.x;
  const int lane = tid & 63;
  const int w = tid >> 6;
  const int ln = lane & 15, kg = lane >> 4;
  const int m0 = blockIdx.x * 128;
  const int n0 = blockIdx.y * 128;
  const int mi = (w & 1) * 64, ni = (w >> 1) * 64;

  f32x4 acc[4][4] = {};
  float bias[4];
#pragma unroll
  for (int nj = 0; nj < 4; ++nj) bias[nj] = bi[n0 + ni + nj * 16 + ln] + bh[n0 + ni + nj * 16 + ln];

  const int lrow = lane >> 3;
  const int lcol = (lane & 7) * 8;

  for (int kt = 0; kt < 512; kt += 64) {
#pragma unroll
    for (int i = 0; i < 4; ++i) {
      int row = i * 32 + w * 8;
      const u16* ga = A + (long)(m0 + row + lrow) * 512 + kt + lcol;
      __builtin_amdgcn_global_load_lds(GLP(ga), LDSP(As + row * 64), 16, 0, 0);
      const u16* gb = Bw + (long)(n0 + row + lrow) * 512 + kt + lcol;
      __builtin_amdgcn_global_load_lds(GLP(gb), LDSP(Bs + row * 64), 16, 0, 0);
    }
    __syncthreads();
#pragma unroll
    for (int kc = 0; kc < 64; kc += 32) {
      short8 af[4], bf[4];
#pragma unroll
      for (int i = 0; i < 4; ++i) {
        af[i] = *(const short8*)(As + (mi + i * 16 + ln) * 64 + kc + kg * 8);
        bf[i] = *(const short8*)(Bs + (ni + i * 16 + ln) * 64 + kc + kg * 8);
      }
#pragma unroll
      for (int a = 0; a < 4; ++a)
#pragma unroll
        for (int b = 0; b < 4; ++b)
          acc[a][b] = __builtin_amdgcn_mfma_f32_16x16x32_bf16(af[a], bf[b], acc[a][b], 0, 0, 0);
    }
    __syncthreads();
  }
#pragma unroll
  for (int a = 0; a < 4; ++a)
#pragma unroll
    for (int b = 0; b < 4; ++b)
#pragma unroll
      for (int r = 0; r < 4; ++r) {
        int m = m0 + mi + a * 16 + kg * 4 + r;
        int n = n0 + ni + b * 16 + ln;
        C[(long)m * 1024 + n] = f2bf(acc[a][b][r] + bias[b]);
      }
}

// ---------------- persistent pipelined 2-layer recurrence --------------------
// 256 blocks x 256 threads. block = (batch_tile q in 0..3) x (unit_tile c in 0..63)
// The 4 batch-groups are fully independent: group barrier spans only the 64
// blocks sharing q. All h traffic + flags go LLC-direct (sc0 sc1), no fences.
__global__ __launch_bounds__(256, 1) void rnn_persist(
    const u16* __restrict__ whh0, const u16* __restrict__ wih1,
    const u16* __restrict__ whh1, const u16* __restrict__ xp0,
    const float* __restrict__ bih1, const float* __restrict__ bhh1,
    u16* __restrict__ h1buf, u16* __restrict__ h2buf, int* __restrict__ bar) {
  const int tid = threadIdx.x;
  const int lane = tid & 63;
  const int w = tid >> 6;
  const int ln = lane & 15, kg = lane >> 4;
  const int q = blockIdx.x >> 6;
  const int m0 = q * 16;
  const int j0 = (blockIdx.x & 63) * 16;
  const int kb = w * 256;  // this wave's K-chunk base (K split 4 ways)

  // persistent weight fragments (B-operand layout: n=lane&15 -> row j0+ln)
  short8 WA[8], W1[8], W2[8];
#pragma unroll
  for (int i = 0; i < 8; ++i) {
    int off = (j0 + ln) * 1024 + kb + i * 32 + kg * 8;
    WA[i] = *(const short8*)(whh0 + off);
    W1[i] = *(const short8*)(wih1 + off);
    W2[i] = *(const short8*)(whh1 + off);
  }
  const float bias1 = bih1[j0 + ln] + bhh1[j0 + ln];

  __shared__ float red[2][4][256];
  int* flags = bar + 64 + q * 64;  // this group's 64 flags (256B-aligned)
  const int hoff = (m0 + ln) * 1024 + kb + kg * 8;  // A-operand: m=lane&15 -> batch

  for (int it = 0; it <= 512; ++it) {
    // prefetch xp0[.,it,.] early (plain cached loads; hidden under H loads)
    u16 xpv[4];
    if (w == 0 && it < 512) {
#pragma unroll
      for (int r = 0; r < 4; ++r)
        xpv[r] = xp0[((long)(m0 + kg * 4 + r) * 512 + it) * 1024 + j0 + ln];
    }
    const u16* h1p = h1buf + ((it + 1) & 1) * 65536 + hoff;  // h1[it-1]
    const u16* h2p = h2buf + (it & 1) * 65536 + hoff;        // h2[it-2]
    short8 H1[8], H2[8];
    load_h_tiles(h1p, h2p, H1[0], H1[1], H1[2], H1[3], H1[4], H1[5], H1[6], H1[7],
                 H2[0], H2[1], H2[2], H2[3], H2[4], H2[5], H2[6], H2[7]);
    f32x4 accA = {}, accB = {};
#pragma unroll
    for (int i = 0; i < 8; ++i) accA = __builtin_amdgcn_mfma_f32_16x16x32_bf16(H1[i], WA[i], accA, 0, 0, 0);
#pragma unroll
    for (int i = 0; i < 8; ++i) accB = __builtin_amdgcn_mfma_f32_16x16x32_bf16(H1[i], W1[i], accB, 0, 0, 0);
#pragma unroll
    for (int i = 0; i < 8; ++i) accB = __builtin_amdgcn_mfma_f32_16x16x32_bf16(H2[i], W2[i], accB, 0, 0, 0);
    *(f32x4*)&red[0][w][lane * 4] = accA;
    *(f32x4*)&red[1][w][lane * 4] = accB;
    __syncthreads();

    if (w == 0) {
      if (it < 512) {  // epilogue layer 0 -> h1[it]
        f32x4 s = *(const f32x4*)&red[0][0][lane * 4];
        s += *(const f32x4*)&red[0][1][lane * 4];
        s += *(const f32x4*)&red[0][2][lane * 4];
        s += *(const f32x4*)&red[0][3][lane * 4];
        u16* h1w = h1buf + (it & 1) * 65536;
#pragma unroll
        for (int r = 0; r < 4; ++r) {
          int mb = m0 + kg * 4 + r;  // D layout: row=(lane>>4)*4+r, col=lane&15
          float z = s[r] + bf2f(xpv[r]);
          store_short_sc(h1w + mb * 1024 + j0 + ln, (unsigned)f2bf(tanh_fast(z)));
        }
        asm volatile("s_waitcnt vmcnt(0)" ::: "memory");
      }
    } else if (w == 1) {
      if (it >= 1) {  // epilogue layer 1 -> h2[it-1]
        f32x4 s = *(const f32x4*)&red[1][0][lane * 4];
        s += *(const f32x4*)&red[1][1][lane * 4];
        s += *(const f32x4*)&red[1][2][lane * 4];
        s += *(const f32x4*)&red[1][3][lane * 4];
        u16* h2w = h2buf + ((it + 1) & 1) * 65536;
#pragma unroll
        for (int r = 0; r < 4; ++r) {
          int mb = m0 + kg * 4 + r;
          float z = s[r] + bias1;
          store_short_sc(h2w + mb * 1024 + j0 + ln, (unsigned)f2bf(tanh_fast(z)));
        }
        asm volatile("s_waitcnt vmcnt(0)" ::: "memory");
      }
    }
    __syncthreads();  // all h stores for step `it` are at the LLC

    if (it < 512) {
      if (tid == 0) store_int_sc(&flags[blockIdx.x & 63], it + 1);
      if (tid < 64) {
        const int* fp = &flags[tid];
        while (load_int_sc(fp) < it + 1) {}
      }
      __syncthreads();
    }
  }
}

// ---------------- FC head: out[b] = sigmoid(h2[511][b,:] . fc_w + fc_b) ------
__global__ __launch_bounds__(256) void fc_kernel(const u16* __restrict__ h2,
                                                 const float* __restrict__ fcw,
                                                 const float* __restrict__ fcb,
                                                 float* __restrict__ out) {
  const int lane = threadIdx.x & 63;
  const int w = threadIdx.x >> 6;
  float wreg[16];
#pragma unroll
  for (int i = 0; i < 16; ++i) wreg[i] = fcw[lane * 16 + i];
  for (int b = w; b < 64; b += 4) {
    const u16* hp = h2 + b * 1024 + lane * 16;
    float s = 0.f;
#pragma unroll
    for (int i = 0; i < 16; ++i) s += bf2f(hp[i]) * wreg[i];
#pragma unroll
    for (int off = 32; off > 0; off >>= 1) s += __shfl_down(s, off, 64);
    if (lane == 0) out[b] = 1.0f / (1.0f + __expf(-(s + fcb[0])));
  }
}

extern "C" void kernel_launch(void* const* d_in, const int* in_sizes, int n_in,
                              void* d_out, int out_size, void* d_ws, size_t ws_size,
                              hipStream_t stream) {
  const float* x    = (const float*)d_in[0];
  const float* wih0 = (const float*)d_in[1];
  const float* whh0 = (const float*)d_in[2];
  const float* bih0 = (const float*)d_in[3];
  const float* bhh0 = (const float*)d_in[4];
  const float* wih1 = (const float*)d_in[5];
  const float* whh1 = (const float*)d_in[6];
  const float* bih1 = (const float*)d_in[7];
  const float* bhh1 = (const float*)d_in[8];
  const float* fcw  = (const float*)d_in[9];
  const float* fcb  = (const float*)d_in[10];

  char* ws = (char*)d_ws;
  u16* xb    = (u16*)(ws);                  // 33,554,432 B
  u16* wih0b = (u16*)(ws + 33554432);       //  1,048,576 B
  u16* whh0b = (u16*)(ws + 34603008);       //  2,097,152 B
  u16* wih1b = (u16*)(ws + 36700160);       //  2,097,152 B
  u16* whh1b = (u16*)(ws + 38797312);       //  2,097,152 B
  u16* xp0   = (u16*)(ws + 40894464);       // 67,108,864 B
  u16* h1buf = (u16*)(ws + 108003328);      //    262,144 B (2 parities)
  u16* h2buf = (u16*)(ws + 108265472);      //    262,144 B (2 parities)
  int* bar   = (int*)(ws + 108527616);      //      2,048 B

  prep_kernel<<<1024, 256, 0, stream>>>(x, wih0, whh0, wih1, whh1, xb, wih0b,
                                        whh0b, wih1b, whh1b, h1buf, bar);
  dim3 gg(256, 8);
  gemm_xproj<<<gg, 256, 0, stream>>>(xb, wih0b, bih0, bhh0, xp0);
  rnn_persist<<<256, 256, 0, stream>>>(whh0b, wih1b, whh1b, xp0, bih1, bhh1,
                                       h1buf, h2buf, bar);
  fc_kernel<<<1, 256, 0, stream>>>(h2buf + 65536, fcw, fcb, (float*)d_out);
}

// Round 5
// 2137.230 us; speedup vs baseline: 3.5700x; 1.6673x over previous
//
#include <hip/hip_runtime.h>

typedef unsigned short u16;
typedef __attribute__((ext_vector_type(8))) short short8;
typedef __attribute__((ext_vector_type(4))) float f32x4;

#define GLP(p) ((const __attribute__((address_space(1))) void*)(p))
#define LDSP(p) ((__attribute__((address_space(3))) void*)(p))

__device__ inline u16 f2bf(float f) {
  unsigned u = __float_as_uint(f);
  return (u16)((u + 0x7fffu + ((u >> 16) & 1u)) >> 16);
}
__device__ inline float bf2f(u16 h) {
  return __uint_as_float(((unsigned)h) << 16);
}
__device__ inline float tanh_fast(float x) {
  float e = __expf(2.0f * x);
  return 1.0f - 2.0f / (e + 1.0f);
}

// ---- LLC-direct (coherence point) access helpers: sc0 sc1 bypass L1/L2 ------
__device__ inline void store_short_sc(u16* p, unsigned v) {
  asm volatile("global_store_short %0, %1, off sc0 sc1" :: "v"(p), "v"(v) : "memory");
}
__device__ inline void store_int_sc(int* p, int v) {
  asm volatile("global_store_dword %0, %1, off sc0 sc1" :: "v"(p), "v"(v) : "memory");
}
__device__ inline int load_int_sc(const int* p) {
  int v;
  asm volatile("global_load_dword %0, %1, off sc0 sc1\n\t"
               "s_waitcnt vmcnt(0)"
               : "=&v"(v) : "v"(p) : "memory");
  return v;
}
// issue 8 LLC-direct 16B loads (no wait): d[i] from {plo,phi} + i*1024B
__device__ inline void load8_sc(const u16* plo, const u16* phi,
                                short8& d0, short8& d1, short8& d2, short8& d3,
                                short8& d4, short8& d5, short8& d6, short8& d7) {
  asm volatile(
      "global_load_dwordx4 %0, %8, off sc0 sc1\n\t"
      "global_load_dwordx4 %1, %8, off offset:1024 sc0 sc1\n\t"
      "global_load_dwordx4 %2, %8, off offset:2048 sc0 sc1\n\t"
      "global_load_dwordx4 %3, %8, off offset:3072 sc0 sc1\n\t"
      "global_load_dwordx4 %4, %9, off sc0 sc1\n\t"
      "global_load_dwordx4 %5, %9, off offset:1024 sc0 sc1\n\t"
      "global_load_dwordx4 %6, %9, off offset:2048 sc0 sc1\n\t"
      "global_load_dwordx4 %7, %9, off offset:3072 sc0 sc1\n\t"
      : "=&v"(d0), "=&v"(d1), "=&v"(d2), "=&v"(d3),
        "=&v"(d4), "=&v"(d5), "=&v"(d6), "=&v"(d7)
      : "v"(plo), "v"(phi)
      : "memory");
}
// drain all outstanding vmem; ties the 16 fragment values so MFMAs can't hoist
__device__ inline void wait_all16(short8& a0, short8& a1, short8& a2, short8& a3,
                                  short8& a4, short8& a5, short8& a6, short8& a7,
                                  short8& b0, short8& b1, short8& b2, short8& b3,
                                  short8& b4, short8& b5, short8& b6, short8& b7) {
  asm volatile("s_waitcnt vmcnt(0)"
               : "+v"(a0), "+v"(a1), "+v"(a2), "+v"(a3),
                 "+v"(a4), "+v"(a5), "+v"(a6), "+v"(a7),
                 "+v"(b0), "+v"(b1), "+v"(b2), "+v"(b3),
                 "+v"(b4), "+v"(b5), "+v"(b6), "+v"(b7)
               :: "memory");
}
// poll 64 per-producer flags (128B stride) until all >= target
__device__ inline void poll_flags(const int* fbase, int lane, int target) {
  const int* fp = fbase + lane * 32;
  while (load_int_sc(fp) < target) {}
}

// ---------------- prep: fp32 -> bf16 conversions, zero h buffers & flags -----
__device__ inline void convseg(const float* __restrict__ s, u16* __restrict__ d,
                               long n4, long t, long S) {
  for (long i = t; i < n4; i += S) {
    float4 v = ((const float4*)s)[i];
    ushort4 o;
    o.x = f2bf(v.x); o.y = f2bf(v.y); o.z = f2bf(v.z); o.w = f2bf(v.w);
    ((ushort4*)d)[i] = o;
  }
}

__global__ __launch_bounds__(256) void prep_kernel(
    const float* __restrict__ x, const float* __restrict__ wih0,
    const float* __restrict__ whh0, const float* __restrict__ wih1,
    const float* __restrict__ whh1,
    u16* __restrict__ xb, u16* __restrict__ wih0b, u16* __restrict__ whh0b,
    u16* __restrict__ wih1b, u16* __restrict__ whh1b,
    u16* __restrict__ hbufs, int* __restrict__ bar) {
  long t = blockIdx.x * 256L + threadIdx.x;
  long S = (long)gridDim.x * 256L;
  convseg(x,    xb,    16777216 / 4, t, S);
  convseg(wih0, wih0b,   524288 / 4, t, S);
  convseg(whh0, whh0b,  1048576 / 4, t, S);
  convseg(wih1, wih1b,  1048576 / 4, t, S);
  convseg(whh1, whh1b,  1048576 / 4, t, S);
  // zero h1(2 parities) + h2(2 parities): 524288 B = 65536 ushort4
  ushort4 z4 = make_ushort4(0, 0, 0, 0);
  for (long i = t; i < 65536; i += S) ((ushort4*)hbufs)[i] = z4;
  // zero flagsA+flagsB: 16384 ints = 4096 int4
  int4 zi = make_int4(0, 0, 0, 0);
  for (long i = t; i < 4096; i += S) ((int4*)bar)[i] = zi;
}

// ---------------- GEMM: xp0[m][n] = sum_k x[m][k]*Wih0[n][k] + bih0[n]+bhh0[n]
// M=32768, N=1024, K=512; bf16 in, bf16 out (fp32 accum)
__global__ __launch_bounds__(256, 2) void gemm_xproj(
    const u16* __restrict__ A,   // 32768 x 512
    const u16* __restrict__ Bw,  // 1024 x 512
    const float* __restrict__ bi, const float* __restrict__ bh,
    u16* __restrict__ C) {       // 32768 x 1024
  __shared__ u16 As[128 * 64];
  __shared__ u16 Bs[128 * 64];
  const int tid = threadIdx.x;
  const int lane = tid & 63;
  const int w = tid >> 6;
  const int ln = lane & 15, kg = lane >> 4;
  const int m0 = blockIdx.x * 128;
  const int n0 = blockIdx.y * 128;
  const int mi = (w & 1) * 64, ni = (w >> 1) * 64;

  f32x4 acc[4][4] = {};
  float bias[4];
#pragma unroll
  for (int nj = 0; nj < 4; ++nj) bias[nj] = bi[n0 + ni + nj * 16 + ln] + bh[n0 + ni + nj * 16 + ln];

  const int lrow = lane >> 3;
  const int lcol = (lane & 7) * 8;

  for (int kt = 0; kt < 512; kt += 64) {
#pragma unroll
    for (int i = 0; i < 4; ++i) {
      int row = i * 32 + w * 8;
      const u16* ga = A + (long)(m0 + row + lrow) * 512 + kt + lcol;
      __builtin_amdgcn_global_load_lds(GLP(ga), LDSP(As + row * 64), 16, 0, 0);
      const u16* gb = Bw + (long)(n0 + row + lrow) * 512 + kt + lcol;
      __builtin_amdgcn_global_load_lds(GLP(gb), LDSP(Bs + row * 64), 16, 0, 0);
    }
    __syncthreads();
#pragma unroll
    for (int kc = 0; kc < 64; kc += 32) {
      short8 af[4], bf[4];
#pragma unroll
      for (int i = 0; i < 4; ++i) {
        af[i] = *(const short8*)(As + (mi + i * 16 + ln) * 64 + kc + kg * 8);
        bf[i] = *(const short8*)(Bs + (ni + i * 16 + ln) * 64 + kc + kg * 8);
      }
#pragma unroll
      for (int a = 0; a < 4; ++a)
#pragma unroll
        for (int b = 0; b < 4; ++b)
          acc[a][b] = __builtin_amdgcn_mfma_f32_16x16x32_bf16(af[a], bf[b], acc[a][b], 0, 0, 0);
    }
    __syncthreads();
  }
#pragma unroll
  for (int a = 0; a < 4; ++a)
#pragma unroll
    for (int b = 0; b < 4; ++b)
#pragma unroll
      for (int r = 0; r < 4; ++r) {
        int m = m0 + mi + a * 16 + kg * 4 + r;
        int n = n0 + ni + b * 16 + ln;
        C[(long)m * 1024 + n] = f2bf(acc[a][b][r] + bias[b]);
      }
}

// ---------------- persistent pipelined 2-layer recurrence --------------------
// 256 blocks x 256 threads; block = (q in 0..3) x (c in 0..63); group = 64
// blocks sharing q (batch rows q*16..+16). h bufs are TILE-BLOCKED: per parity
// per q, tile c is a contiguous 512B [16 mb][16 jj] region owned exclusively
// by producer block (q,c). Flags padded to 128B/producer; flagA = h1 done,
// flagB = h2 done. One __syncthreads per iteration (LDS red double-buffered);
// flag polling doubles as the inter- AND intra-block barrier.
__global__ __launch_bounds__(256, 1) void rnn_persist(
    const u16* __restrict__ whh0, const u16* __restrict__ wih1,
    const u16* __restrict__ whh1, const u16* __restrict__ xp0,
    const float* __restrict__ bih1, const float* __restrict__ bhh1,
    u16* __restrict__ h1buf, u16* __restrict__ h2buf, int* __restrict__ bar) {
  const int tid = threadIdx.x;
  const int lane = tid & 63;
  const int w = tid >> 6;
  const int ln = lane & 15, kg = lane >> 4;
  const int q = blockIdx.x >> 6;
  const int c = blockIdx.x & 63;
  const int m0 = q * 16;
  const int j0 = c * 16;
  const int kb = w * 256;  // this wave's K-chunk base (K split 4 ways)

  // persistent weight fragments (B-operand layout: n=lane&15 -> row j0+ln)
  short8 WA[8], W1[8], W2[8];
#pragma unroll
  for (int i = 0; i < 8; ++i) {
    int off = (j0 + ln) * 1024 + kb + i * 32 + kg * 8;
    WA[i] = *(const short8*)(whh0 + off);
    W1[i] = *(const short8*)(wih1 + off);
    W2[i] = *(const short8*)(whh1 + off);
  }
  const float bias1 = bih1[j0 + ln] + bhh1[j0 + ln];

  __shared__ float red[2][2][4][256];  // [it parity][layer][wave][lane*4]
  int* flagsA = bar + q * 64 * 32;            // 64 flags, 128B stride
  int* flagsB = bar + 8192 + q * 64 * 32;
  int* myA = flagsA + c * 32;
  int* myB = flagsB + c * 32;

  // consumer A-fragment base (tiled layout), per wave/lane:
  // elem = (w*16 + (kg>>1) + i*2)*256 + ln*16 + (kg&1)*8, i advances by 512
  const int lbase = (w * 16 + (kg >> 1)) * 256 + ln * 16 + (kg & 1) * 8;
  const u16* hq1 = h1buf + q * 16384 + lbase;  // + parity*65536
  const u16* hq2 = h2buf + q * 16384 + lbase;

  short8 H1[8], H2[8];
  u16 xpv[4];

  // ---- pre-loop loads for it=0: h1[-1] parity 1, h2[-2] parity 0 (zeroed) --
  {
    const u16* p1 = hq1 + 65536;
    const u16* p2 = hq2;
    load8_sc(p1, p1 + 2048, H1[0], H1[1], H1[2], H1[3], H1[4], H1[5], H1[6], H1[7]);
    load8_sc(p2, p2 + 2048, H2[0], H2[1], H2[2], H2[3], H2[4], H2[5], H2[6], H2[7]);
    if (w == 0) {
#pragma unroll
      for (int r = 0; r < 4; ++r)
        xpv[r] = xp0[((long)(m0 + kg * 4 + r) * 512 + 0) * 1024 + j0 + ln];
    }
    wait_all16(H1[0], H1[1], H1[2], H1[3], H1[4], H1[5], H1[6], H1[7],
               H2[0], H2[1], H2[2], H2[3], H2[4], H2[5], H2[6], H2[7]);
  }

  for (int it = 0; it <= 512; ++it) {
    const int rp = it & 1;
    f32x4 accA = {}, accB = {};
#pragma unroll
    for (int i = 0; i < 8; ++i) accA = __builtin_amdgcn_mfma_f32_16x16x32_bf16(H1[i], WA[i], accA, 0, 0, 0);
#pragma unroll
    for (int i = 0; i < 8; ++i) accB = __builtin_amdgcn_mfma_f32_16x16x32_bf16(H1[i], W1[i], accB, 0, 0, 0);
#pragma unroll
    for (int i = 0; i < 8; ++i) accB = __builtin_amdgcn_mfma_f32_16x16x32_bf16(H2[i], W2[i], accB, 0, 0, 0);
    *(f32x4*)&red[rp][0][w][lane * 4] = accA;
    *(f32x4*)&red[rp][1][w][lane * 4] = accB;
    __syncthreads();  // the ONLY workgroup barrier this iteration

    if (w == 0) {
      if (it < 512) {  // epilogue layer 0 -> h1[it] (tile-blocked, exclusive)
        f32x4 s = *(const f32x4*)&red[rp][0][0][lane * 4];
        s += *(const f32x4*)&red[rp][0][1][lane * 4];
        s += *(const f32x4*)&red[rp][0][2][lane * 4];
        s += *(const f32x4*)&red[rp][0][3][lane * 4];
        u16* h1w = h1buf + (it & 1) * 65536 + q * 16384 + c * 256;
#pragma unroll
        for (int r = 0; r < 4; ++r) {
          float z = s[r] + bf2f(xpv[r]);  // D layout: row=kg*4+r, col=ln
          store_short_sc(h1w + (kg * 4 + r) * 16 + ln, (unsigned)f2bf(tanh_fast(z)));
        }
        asm volatile("s_waitcnt vmcnt(0)" ::: "memory");
        if (lane == 0) store_int_sc(myA, it + 1);
      }
    } else if (w == 1) {
      if (it >= 1) {  // epilogue layer 1 -> h2[it-1]
        f32x4 s = *(const f32x4*)&red[rp][1][0][lane * 4];
        s += *(const f32x4*)&red[rp][1][1][lane * 4];
        s += *(const f32x4*)&red[rp][1][2][lane * 4];
        s += *(const f32x4*)&red[rp][1][3][lane * 4];
        u16* h2w = h2buf + ((it + 1) & 1) * 65536 + q * 16384 + c * 256;
#pragma unroll
        for (int r = 0; r < 4; ++r) {
          float z = s[r] + bias1;
          store_short_sc(h2w + (kg * 4 + r) * 16 + ln, (unsigned)f2bf(tanh_fast(z)));
        }
        asm volatile("s_waitcnt vmcnt(0)" ::: "memory");
      }
      if (lane == 0) store_int_sc(myB, it + 1);  // it=0: h2[-1] prezeroed
    }

    if (it < 512) {
      // poll h1[it] ready -> issue H1 loads -> poll h2[it-1] -> issue H2 loads
      poll_flags(flagsA, lane, it + 1);
      const u16* p1 = hq1 + (it & 1) * 65536;
      load8_sc(p1, p1 + 2048, H1[0], H1[1], H1[2], H1[3], H1[4], H1[5], H1[6], H1[7]);
      poll_flags(flagsB, lane, it + 1);
      const u16* p2 = hq2 + ((it + 1) & 1) * 65536;
      load8_sc(p2, p2 + 2048, H2[0], H2[1], H2[2], H2[3], H2[4], H2[5], H2[6], H2[7]);
      if (w == 0 && it < 511) {
#pragma unroll
        for (int r = 0; r < 4; ++r)
          xpv[r] = xp0[((long)(m0 + kg * 4 + r) * 512 + (it + 1)) * 1024 + j0 + ln];
      }
      wait_all16(H1[0], H1[1], H1[2], H1[3], H1[4], H1[5], H1[6], H1[7],
                 H2[0], H2[1], H2[2], H2[3], H2[4], H2[5], H2[6], H2[7]);
    }
  }
}

// ---------------- FC head: out[b] = sigmoid(h2[511][b,:] . fc_w + fc_b) ------
// h2[511] lives at parity 1 in the tiled layout.
__global__ __launch_bounds__(256) void fc_kernel(const u16* __restrict__ h2,
                                                 const float* __restrict__ fcw,
                                                 const float* __restrict__ fcb,
                                                 float* __restrict__ out) {
  const int lane = threadIdx.x & 63;
  const int w = threadIdx.x >> 6;
  float wreg[16];
#pragma unroll
  for (int i = 0; i < 16; ++i) wreg[i] = fcw[lane * 16 + i];
  for (int b = w; b < 64; b += 4) {
    const int q = b >> 4, mb = b & 15;
    const u16* hp = h2 + 65536 + q * 16384 + lane * 256 + mb * 16;  // parity 1
    float s = 0.f;
#pragma unroll
    for (int i = 0; i < 16; ++i) s += bf2f(hp[i]) * wreg[i];
#pragma unroll
    for (int off = 32; off > 0; off >>= 1) s += __shfl_down(s, off, 64);
    if (lane == 0) out[b] = 1.0f / (1.0f + __expf(-(s + fcb[0])));
  }
}

extern "C" void kernel_launch(void* const* d_in, const int* in_sizes, int n_in,
                              void* d_out, int out_size, void* d_ws, size_t ws_size,
                              hipStream_t stream) {
  const float* x    = (const float*)d_in[0];
  const float* wih0 = (const float*)d_in[1];
  const float* whh0 = (const float*)d_in[2];
  const float* bih0 = (const float*)d_in[3];
  const float* bhh0 = (const float*)d_in[4];
  const float* wih1 = (const float*)d_in[5];
  const float* whh1 = (const float*)d_in[6];
  const float* bih1 = (const float*)d_in[7];
  const float* bhh1 = (const float*)d_in[8];
  const float* fcw  = (const float*)d_in[9];
  const float* fcb  = (const float*)d_in[10];

  char* ws = (char*)d_ws;
  u16* xb    = (u16*)(ws);                  // 33,554,432 B
  u16* wih0b = (u16*)(ws + 33554432);       //  1,048,576 B
  u16* whh0b = (u16*)(ws + 34603008);       //  2,097,152 B
  u16* wih1b = (u16*)(ws + 36700160);       //  2,097,152 B
  u16* whh1b = (u16*)(ws + 38797312);       //  2,097,152 B
  u16* xp0   = (u16*)(ws + 40894464);       // 67,108,864 B
  u16* h1buf = (u16*)(ws + 108003328);      //    262,144 B (2 parities, tiled)
  u16* h2buf = (u16*)(ws + 108265472);      //    262,144 B (2 parities, tiled)
  int* bar   = (int*)(ws + 108527616);      //     65,536 B (padded flags A+B)

  prep_kernel<<<1024, 256, 0, stream>>>(x, wih0, whh0, wih1, whh1, xb, wih0b,
                                        whh0b, wih1b, whh1b, h1buf, bar);
  dim3 gg(256, 8);
  gemm_xproj<<<gg, 256, 0, stream>>>(xb, wih0b, bih0, bhh0, xp0);
  rnn_persist<<<256, 256, 0, stream>>>(whh0b, wih1b, whh1b, xp0, bih1, bhh1,
                                       h1buf, h2buf, bar);
  fc_kernel<<<1, 256, 0, stream>>>(h2buf, fcw, fcb, (float*)d_out);
}